// Round 5
// baseline (3469.278 us; speedup 1.0000x reference)
//
#include <hip/hip_runtime.h>
#include <hip/hip_bf16.h>
#include <math.h>

typedef __hip_bfloat16 bf16;
typedef __attribute__((ext_vector_type(8))) __bf16 bf16x8;
typedef __attribute__((ext_vector_type(4))) float f32x4;

#define HDIM 768
#define MROWS 6144
#define NCHUNK 6

__device__ __forceinline__ float bf2f(unsigned int u) {
  union { unsigned int i; float f; } c; c.i = u << 16; return c.f;
}

__device__ __forceinline__ void gload16(const void* g, void* l) {
  __builtin_amdgcn_global_load_lds((const __attribute__((address_space(1))) void*)g,
                                   (__attribute__((address_space(3))) void*)l, 16, 0, 0);
}

// overflow-safe tanh-approx GELU (error ~1e-3 abs)
__device__ __forceinline__ float gelu_f(float v) {
  const float u2 = 1.5957691216057308f * (v + 0.044715f * v * v * v);
  const float e = __expf(u2);
  const float th = 1.f - 2.f / (e + 1.f);
  return 0.5f * v * (1.f + th);
}

// ---------------- weight transpose + f32->bf16 convert ----------------
__global__ __launch_bounds__(256) void wconv(
    const float* __restrict__ Wq, const float* __restrict__ Wk,
    const float* __restrict__ Wv, const float* __restrict__ Wo,
    const float* __restrict__ Wi, const float* __restrict__ Wo2,
    bf16* __restrict__ wt)
{
  __shared__ float tile[32][33];
  const int bid = blockIdx.x;
  const float* src; bf16* dst; int K, N, tIdx;
  if (bid < 2304) {
    int m = bid / 576; tIdx = bid % 576; K = 768; N = 768;
    src = (m == 0) ? Wq : (m == 1) ? Wk : (m == 2) ? Wv : Wo;
    dst = wt + (size_t)m * 589824;
  } else if (bid < 4608) {
    tIdx = bid - 2304; K = 768; N = 3072; src = Wi; dst = wt + 2359296;
  } else {
    tIdx = bid - 4608; K = 3072; N = 768; src = Wo2; dst = wt + 4718592;
  }
  const int tilesN = N >> 5;
  const int tn = tIdx % tilesN, tk = tIdx / tilesN;
  const int n0 = tn * 32, k0 = tk * 32;
  const int tx = threadIdx.x & 31, ty = threadIdx.x >> 5;
#pragma unroll
  for (int r = 0; r < 4; ++r)
    tile[ty + r * 8][tx] = src[(size_t)(k0 + ty + r * 8) * N + n0 + tx];
  __syncthreads();
#pragma unroll
  for (int r = 0; r < 4; ++r)
    dst[(size_t)(n0 + ty + r * 8) * K + k0 + tx] = __float2bfloat16(tile[tx][ty + r * 8]);
}

// ---------------- GEMM 256x256, 8 waves, BK=64, 2-phase/K-tile counted-vmcnt ----------------
// C = A[M,K](bf16) @ Bt[N,K]^T(bf16) + bias.
// LDS: A,B each [2 dbuf][2 khalf][256 rows x 32 K] = 128 KiB total, 1 block/CU.
// Swizzle: byte ^= ((row>>1)&1)<<5, applied via pre-swizzled GLOBAL source
// (gload_lds dest linear) and swizzled ds_read offsets.
// epi 0: fused QKV -> bf16 (Q scaled 0.125); epi 2: gelu -> bf16; epi 3: f32.
__global__ __launch_bounds__(512, 2) void gemm256(
    const bf16* __restrict__ A, const bf16* __restrict__ Bt,
    void* __restrict__ out, const float* __restrict__ b0,
    const float* __restrict__ b1, const float* __restrict__ b2,
    int gx, int N, int K, int NT, int epi)
{
  __shared__ __align__(16) bf16 As[2][2][8192];   // [dbuf][khalf][256*32]
  __shared__ __align__(16) bf16 Bs[2][2][8192];

  const int nwg = gridDim.x;
  const int wg = blockIdx.x;
  const int L = (wg & 7) * (nwg >> 3) + (wg >> 3);   // XCD-contiguous (nwg%8==0)
  const int bx = L % gx, by = L / gx;
  const int m0 = by * 256, n0 = bx * 256;

  const int t = threadIdx.x;
  const int lane = t & 63;
  const int w = t >> 6;          // 0..7
  const int wr = w >> 2;         // 0..1  (M half)
  const int wc = w & 3;          // 0..3  (N quarter)
  const int fr = lane & 15;
  const int g = lane >> 4;       // 0..3

  f32x4 acc[8][4];
#pragma unroll
  for (int i = 0; i < 8; ++i)
#pragma unroll
    for (int j = 0; j < 4; ++j) acc[i][j] = (f32x4)0.f;

  // staging: thread covers slots {t, t+512} of each 1024-slot (16B) k-half tile.
  // slot s holds logical slot s ^ (((s>>3)&1)<<1)  (byte5 ^= byte7)
  const int sg0 = t ^ (((t >> 3) & 1) << 1);
  const int r0 = sg0 >> 2;           // 0..127 ; second load row = r0+128
  const int kp0 = sg0 & 3;
  const bf16* gA0 = A + (size_t)(m0 + r0) * K + kp0 * 8;
  const bf16* gB0 = Bt + (size_t)(n0 + r0) * K + kp0 * 8;
  const int dst0 = t * 16;

  // frag read byte offsets (within a [256][32] k-half buffer), swizzled
  int offA[8], offB[4];
#pragma unroll
  for (int mf = 0; mf < 8; ++mf) {
    const int R = wr * 128 + mf * 16 + fr;
    offA[mf] = (R * 64 + g * 16) ^ (((R >> 1) & 1) << 5);
  }
#pragma unroll
  for (int nf = 0; nf < 4; ++nf) {
    const int R = wc * 64 + nf * 16 + fr;
    offB[nf] = (R * 64 + g * 16) ^ (((R >> 1) & 1) << 5);
  }

#define STAGE_A(KT, DB, KH) {                                              \
    const bf16* s_ = gA0 + (size_t)(KT) * 64 + (KH) * 32;                  \
    gload16(s_, (char*)As[DB][KH] + dst0);                                 \
    gload16(s_ + (size_t)128 * K, (char*)As[DB][KH] + dst0 + 8192); }
#define STAGE_B(KT, DB, KH) {                                              \
    const bf16* s_ = gB0 + (size_t)(KT) * 64 + (KH) * 32;                  \
    gload16(s_, (char*)Bs[DB][KH] + dst0);                                 \
    gload16(s_ + (size_t)128 * K, (char*)Bs[DB][KH] + dst0 + 8192); }

  // prologue: stage tile 0 (kh0 then kh1) -> 8 outstanding
  STAGE_A(0, 0, 0) STAGE_B(0, 0, 0)
  STAGE_A(0, 0, 1) STAGE_B(0, 0, 1)

#define PHASE(KT, DB, KH) {                                                \
    const int pf_ = ((KT) + 1 < NT) ? (KT) + 1 : NT - 1;                   \
    STAGE_A(pf_, (DB) ^ 1, KH)                                             \
    STAGE_B(pf_, (DB) ^ 1, KH)                                             \
    asm volatile("s_waitcnt vmcnt(8)" ::: "memory");                       \
    asm volatile("s_barrier" ::: "memory");                                \
    bf16x8 af[8], bfr[4];                                                  \
    _Pragma("unroll")                                                      \
    for (int mf = 0; mf < 8; ++mf)                                         \
      af[mf] = *(const bf16x8*)((const char*)As[DB][KH] + offA[mf]);       \
    _Pragma("unroll")                                                      \
    for (int nf = 0; nf < 4; ++nf)                                         \
      bfr[nf] = *(const bf16x8*)((const char*)Bs[DB][KH] + offB[nf]);      \
    __builtin_amdgcn_s_setprio(1);                                         \
    _Pragma("unroll")                                                      \
    for (int mf = 0; mf < 8; ++mf)                                         \
      _Pragma("unroll")                                                    \
      for (int nf = 0; nf < 4; ++nf)                                       \
        acc[mf][nf] = __builtin_amdgcn_mfma_f32_16x16x32_bf16(af[mf], bfr[nf], acc[mf][nf], 0, 0, 0); \
    __builtin_amdgcn_s_setprio(0);                                         \
  }

#pragma unroll 1
  for (int kt = 0; kt < NT; kt += 2) {   // NT even for all shapes (12 or 48)
    PHASE(kt, 0, 0)
    PHASE(kt, 0, 1)
    PHASE(kt + 1, 1, 0)
    PHASE(kt + 1, 1, 1)
  }
  asm volatile("s_waitcnt vmcnt(0)" ::: "memory");
#undef PHASE
#undef STAGE_A
#undef STAGE_B

  const int rr = (lane >> 4) * 4;
  const int cc0 = lane & 15;
  if (epi == 0) {
    const int mat = n0 / HDIM;                 // 768 % 256 == 0 -> uniform
    const float* bias = (mat == 0) ? b0 : (mat == 1) ? b1 : b2;
    const float qs = (mat == 0) ? 0.125f : 1.0f;
    bf16* dst = (bf16*)out + (size_t)mat * MROWS * HDIM;
    const int nl = n0 - mat * HDIM;
#pragma unroll
    for (int mf = 0; mf < 8; ++mf)
#pragma unroll
      for (int nf = 0; nf < 4; ++nf) {
        const int row = m0 + wr * 128 + mf * 16 + rr;
        const int col = nl + wc * 64 + nf * 16 + cc0;
        const float bv = bias[col];
#pragma unroll
        for (int r = 0; r < 4; ++r)
          dst[(size_t)(row + r) * HDIM + col] = __float2bfloat16((acc[mf][nf][r] + bv) * qs);
      }
  } else if (epi == 2) {
    bf16* dst = (bf16*)out;
#pragma unroll
    for (int mf = 0; mf < 8; ++mf)
#pragma unroll
      for (int nf = 0; nf < 4; ++nf) {
        const int row = m0 + wr * 128 + mf * 16 + rr;
        const int col = n0 + wc * 64 + nf * 16 + cc0;
        const float bv = b0[col];
#pragma unroll
        for (int r = 0; r < 4; ++r)
          dst[(size_t)(row + r) * N + col] = __float2bfloat16(gelu_f(acc[mf][nf][r] + bv));
      }
  } else {
    float* dst = (float*)out;
#pragma unroll
    for (int mf = 0; mf < 8; ++mf)
#pragma unroll
      for (int nf = 0; nf < 4; ++nf) {
        const int row = m0 + wr * 128 + mf * 16 + rr;
        const int col = n0 + wc * 64 + nf * 16 + cc0;
        const float bv = b0[col];
#pragma unroll
        for (int r = 0; r < 4; ++r)
          dst[(size_t)(row + r) * N + col] = acc[mf][nf][r] + bv;
      }
  }
}

// ---------------- MFMA sliding-window attention ----------------
__global__ __launch_bounds__(256) void attn_mfma(
    const bf16* __restrict__ qkv, bf16* __restrict__ attb)
{
  const int c = blockIdx.x, h = blockIdx.y, b = blockIdx.z;
  __shared__ unsigned int Vtw[64 * 64];
  __shared__ __align__(16) bf16 Pl[4][32 * 40];
  const int t = threadIdx.x;
  const int lane = t & 63;
  const int w = t >> 6;
  const int fr = lane & 15;
  const int g = lane >> 4;
  const bf16* Km = qkv + (size_t)4718592;
  const bf16* Vm = qkv + (size_t)9437184;
  const size_t qrow0 = (size_t)(b * 768 + c * 128);

  bf16x8 qf[2][2];
#pragma unroll
  for (int nt = 0; nt < 2; ++nt)
#pragma unroll
    for (int ks = 0; ks < 2; ++ks)
      qf[nt][ks] = *(const bf16x8*)(qkv + (qrow0 + w * 32 + nt * 16 + fr) * HDIM + h * 64 + ks * 32 + g * 8);

  f32x4 oacc[4][2];
#pragma unroll
  for (int i = 0; i < 4; ++i) { oacc[i][0] = (f32x4)0.f; oacc[i][1] = (f32x4)0.f; }
  float mrun[2] = {-1e30f, -1e30f};
  float lrun[2] = {0.f, 0.f};

#pragma unroll 1
  for (int cc = c - 1; cc <= c + 1; ++cc) {
    if (cc < 0 || cc >= NCHUNK) continue;
    __syncthreads();
    {
      const int d0 = (t & 7) * 8;
#pragma unroll
      for (int half = 0; half < 2; ++half) {
        const int kp2 = (t >> 3) + half * 32;
        const bf16* vr = Vm + ((size_t)(b * 768 + cc * 128) + kp2 * 2) * HDIM + h * 64 + d0;
        uint4 r0 = *(const uint4*)vr;
        uint4 r1 = *(const uint4*)(vr + HDIM);
        unsigned int a0[4] = {r0.x, r0.y, r0.z, r0.w};
        unsigned int a1[4] = {r1.x, r1.y, r1.z, r1.w};
#pragma unroll
        for (int e = 0; e < 8; ++e) {
          const int d = d0 + e;
          unsigned int lo = (a0[e >> 1] >> ((e & 1) * 16)) & 0xffffu;
          unsigned int hi = (a1[e >> 1] >> ((e & 1) * 16)) & 0xffffu;
          unsigned int byteoff = (unsigned int)(d * 256 + kp2 * 4);
          byteoff ^= ((((d >> 3) ^ d) & 7) << 4);
          Vtw[byteoff >> 2] = lo | (hi << 16);
        }
      }
    }
    __syncthreads();
    const int mode = (cc < c) ? 0 : (cc == c ? 1 : 2);
    const bf16* Kc = Km + ((size_t)(b * 768 + cc * 128)) * HDIM + h * 64;

#pragma unroll 1
    for (int kb = 0; kb < 4; ++kb) {
      f32x4 sacc[2][2];
      sacc[0][0] = sacc[0][1] = sacc[1][0] = sacc[1][1] = (f32x4)0.f;
#pragma unroll
      for (int ks = 0; ks < 2; ++ks)
#pragma unroll
        for (int mt = 0; mt < 2; ++mt) {
          bf16x8 kf = *(const bf16x8*)(Kc + (size_t)(kb * 32 + mt * 16 + fr) * HDIM + ks * 32 + g * 8);
          sacc[mt][0] = __builtin_amdgcn_mfma_f32_16x16x32_bf16(kf, qf[0][ks], sacc[mt][0], 0, 0, 0);
          sacc[mt][1] = __builtin_amdgcn_mfma_f32_16x16x32_bf16(kf, qf[1][ks], sacc[mt][1], 0, 0, 0);
        }
#pragma unroll
      for (int nt = 0; nt < 2; ++nt) {
        const int iq = w * 32 + nt * 16 + fr;
        float pm = -1e30f;
#pragma unroll
        for (int mt = 0; mt < 2; ++mt)
#pragma unroll
          for (int r = 0; r < 4; ++r) {
            const int j = kb * 32 + mt * 16 + g * 4 + r;
            const bool valid = (mode == 1) || (mode == 0 ? (j >= iq) : (j <= iq));
            const float sv = valid ? sacc[mt][nt][r] : -1e30f;
            sacc[mt][nt][r] = sv;
            pm = fmaxf(pm, sv);
          }
        pm = fmaxf(pm, __shfl_xor(pm, 16));
        pm = fmaxf(pm, __shfl_xor(pm, 32));
        const float mnew = fmaxf(fmaxf(mrun[nt], pm), -1e20f);
        const float sc = __expf(mrun[nt] - mnew);
        mrun[nt] = mnew;
        lrun[nt] *= sc;
#pragma unroll
        for (int mt = 0; mt < 4; ++mt) oacc[mt][nt] *= sc;
        float ps = 0.f;
#pragma unroll
        for (int mt = 0; mt < 2; ++mt) {
          union { bf16 hh[4]; uint2 uu; } pk;
#pragma unroll
          for (int r = 0; r < 4; ++r) {
            const float p = __expf(sacc[mt][nt][r] - mnew);
            ps += p;
            pk.hh[r] = __float2bfloat16(p);
          }
          *(uint2*)(&Pl[w][(nt * 16 + fr) * 40 + mt * 16 + g * 4]) = pk.uu;
        }
        ps += __shfl_xor(ps, 16);
        ps += __shfl_xor(ps, 32);
        lrun[nt] += ps;
      }
      bf16x8 bpf[2];
#pragma unroll
      for (int nt = 0; nt < 2; ++nt)
        bpf[nt] = *(const bf16x8*)(&Pl[w][(nt * 16 + fr) * 40 + g * 8]);
#pragma unroll
      for (int mt = 0; mt < 4; ++mt) {
        const int d = mt * 16 + fr;
        unsigned int byteoff = (unsigned int)(d * 256 + kb * 64 + g * 16);
        byteoff ^= ((((d >> 3) ^ d) & 7) << 4);
        bf16x8 vf = *(const bf16x8*)((const char*)Vtw + byteoff);
        oacc[mt][0] = __builtin_amdgcn_mfma_f32_16x16x32_bf16(vf, bpf[0], oacc[mt][0], 0, 0, 0);
        oacc[mt][1] = __builtin_amdgcn_mfma_f32_16x16x32_bf16(vf, bpf[1], oacc[mt][1], 0, 0, 0);
      }
    }
  }
#pragma unroll
  for (int nt = 0; nt < 2; ++nt) {
    const float rl = 1.f / lrun[nt];
    bf16* orow = attb + (qrow0 + w * 32 + nt * 16 + fr) * HDIM + h * 64;
#pragma unroll
    for (int mt = 0; mt < 4; ++mt) {
      union { bf16 hh[4]; uint2 uu; } ok;
#pragma unroll
      for (int r = 0; r < 4; ++r) ok.hh[r] = __float2bfloat16(oacc[mt][nt][r] * rl);
      *(uint2*)(orow + mt * 16 + g * 4) = ok.uu;
    }
  }
}

// ---------------- LayerNorm kernels ----------------
__device__ __forceinline__ void blk_reduce2(float& s1, float& s2) {
#pragma unroll
  for (int o = 32; o > 0; o >>= 1) { s1 += __shfl_xor(s1, o); s2 += __shfl_xor(s2, o); }
  __shared__ float red[8];
  const int w = threadIdx.x >> 6;
  if ((threadIdx.x & 63) == 0) { red[w] = s1; red[4 + w] = s2; }
  __syncthreads();
  s1 = red[0] + red[1] + red[2] + red[3];
  s2 = red[4] + red[5] + red[6] + red[7];
}

__global__ __launch_bounds__(256) void embed_ln(
    const float* __restrict__ emb, const float* __restrict__ pos,
    const float* __restrict__ tte, const float* __restrict__ g,
    const float* __restrict__ bt, float* __restrict__ x, bf16* __restrict__ xb)
{
  const int row = blockIdx.x;
  const int s = row % 768;
  const int t = threadIdx.x;
  const size_t base = (size_t)row * HDIM;
  const size_t pbase = (size_t)(s + 2) * HDIM;
  float v[3];
#pragma unroll
  for (int i = 0; i < 3; ++i) {
    const int idx = t + i * 256;
    v[i] = emb[base + idx] + pos[pbase + idx] + tte[idx];
  }
  float s1 = v[0] + v[1] + v[2];
  float s2 = v[0]*v[0] + v[1]*v[1] + v[2]*v[2];
  blk_reduce2(s1, s2);
  const float mu = s1 * (1.f / 768.f);
  const float var = s2 * (1.f / 768.f) - mu * mu;
  const float inv = rsqrtf(var + 1e-12f);
#pragma unroll
  for (int i = 0; i < 3; ++i) {
    const int idx = t + i * 256;
    const float o = (v[i] - mu) * inv * g[idx] + bt[idx];
    x[base + idx] = o;
    xb[base + idx] = __float2bfloat16(o);
  }
}

__global__ __launch_bounds__(256) void add_ln(
    const float* __restrict__ tmp, float* __restrict__ x, bf16* __restrict__ xb,
    const float* __restrict__ g, const float* __restrict__ bt)
{
  const int row = blockIdx.x;
  const int t = threadIdx.x;
  const size_t base = (size_t)row * HDIM;
  float v[3];
#pragma unroll
  for (int i = 0; i < 3; ++i) {
    const int idx = t + i * 256;
    v[i] = x[base + idx] + tmp[base + idx];
  }
  float s1 = v[0] + v[1] + v[2];
  float s2 = v[0]*v[0] + v[1]*v[1] + v[2]*v[2];
  blk_reduce2(s1, s2);
  const float mu = s1 * (1.f / 768.f);
  const float var = s2 * (1.f / 768.f) - mu * mu;
  const float inv = rsqrtf(var + 1e-12f);
#pragma unroll
  for (int i = 0; i < 3; ++i) {
    const int idx = t + i * 256;
    const float o = (v[i] - mu) * inv * g[idx] + bt[idx];
    x[base + idx] = o;
    xb[base + idx] = __float2bfloat16(o);
  }
}

// ---------------- gate ----------------
__global__ __launch_bounds__(256) void gate_kernel(
    const float* __restrict__ x, const float* __restrict__ gw,
    const float* __restrict__ gb, float* __restrict__ out)
{
  const int row = blockIdx.x * 4 + (threadIdx.x >> 6);
  const int lane = threadIdx.x & 63;
  const float* xr = x + (size_t)row * HDIM;
  float s = 0.f;
#pragma unroll
  for (int i = 0; i < 12; ++i) s += xr[lane + i * 64] * gw[lane + i * 64];
#pragma unroll
  for (int o = 32; o > 0; o >>= 1) s += __shfl_xor(s, o);
  if (lane == 0) out[row] = s + gb[0];
}

// ---------------- host ----------------
extern "C" void kernel_launch(void* const* d_in, const int* in_sizes, int n_in,
                              void* d_out, int out_size, void* d_ws, size_t ws_size,
                              hipStream_t stream)
{
  const float* emb = (const float*)d_in[0];
  const float* pos = (const float*)d_in[2];
  const float* tte = (const float*)d_in[3];
  const float* eg  = (const float*)d_in[4];
  const float* eb  = (const float*)d_in[5];
  const float* Wq  = (const float*)d_in[6];
  const float* bq  = (const float*)d_in[7];
  const float* Wk  = (const float*)d_in[8];
  const float* bk  = (const float*)d_in[9];
  const float* Wv  = (const float*)d_in[10];
  const float* bv  = (const float*)d_in[11];
  const float* Wo  = (const float*)d_in[12];
  const float* bo  = (const float*)d_in[13];
  const float* g1  = (const float*)d_in[14];
  const float* be1 = (const float*)d_in[15];
  const float* Wi  = (const float*)d_in[16];
  const float* bi  = (const float*)d_in[17];
  const float* Wo2 = (const float*)d_in[18];
  const float* bo2 = (const float*)d_in[19];
  const float* g2  = (const float*)d_in[20];
  const float* be2 = (const float*)d_in[21];
  const float* gw  = (const float*)d_in[22];
  const float* gb  = (const float*)d_in[23];

  char* wsp = (char*)d_ws;
  bf16* wt   = (bf16*)wsp;
  bf16* xb   = (bf16*)(wsp + 14155776);
  bf16* qkvb = (bf16*)(wsp + 23592960);
  float* tmp = (float*)(wsp + 61341696);
  bf16* attb = qkvb + (size_t)3 * 4718592;
  bf16* ffb  = qkvb;                 // alias: q/k/v/att dead when FFN1 runs
  float* x   = (float*)d_out;        // f32 residual stream lives in d_out
  float* gate = x + 4718592;

  embed_ln<<<6144, 256, 0, stream>>>(emb, pos, tte, eg, eb, x, xb);

  for (int l = 0; l < 12; ++l) {
    wconv<<<6912, 256, 0, stream>>>(Wq + (size_t)l * 589824, Wk + (size_t)l * 589824,
                                    Wv + (size_t)l * 589824, Wo + (size_t)l * 589824,
                                    Wi + (size_t)l * 2359296, Wo2 + (size_t)l * 2359296, wt);
    // QKV: M=6144 N=2304 K=768 -> 24x9 = 216 blocks
    gemm256<<<216, 512, 0, stream>>>(xb, wt, qkvb,
        bq + l * 768, bk + l * 768, bv + l * 768, 9, 2304, 768, 12, 0);
    attn_mfma<<<dim3(6, 12, 8), 256, 0, stream>>>(qkvb, attb);
    // OProj: N=768 K=768 -> 24x3 = 72 blocks
    gemm256<<<72, 512, 0, stream>>>(attb, wt + 1769472, tmp,
        bo + l * 768, nullptr, nullptr, 3, 768, 768, 12, 3);
    add_ln<<<6144, 256, 0, stream>>>(tmp, x, xb, g1 + l * 768, be1 + l * 768);
    // FFN1: N=3072 K=768 -> 24x12 = 288 blocks
    gemm256<<<288, 512, 0, stream>>>(xb, wt + 2359296, ffb,
        bi + l * 3072, nullptr, nullptr, 12, 3072, 768, 12, 2);
    // FFN2: N=768 K=3072 -> 24x3 = 72 blocks
    gemm256<<<72, 512, 0, stream>>>(ffb, wt + 4718592, tmp,
        bo2 + l * 768, nullptr, nullptr, 3, 768, 3072, 48, 3);
    add_ln<<<6144, 256, 0, stream>>>(tmp, x, xb, g2 + l * 768, be2 + l * 768);
  }

  gate_kernel<<<1536, 256, 0, stream>>>(x, gw, gb, gate);
}

// Round 6
// 3224.678 us; speedup vs baseline: 1.0759x; 1.0759x over previous
//
#include <hip/hip_runtime.h>
#include <hip/hip_bf16.h>
#include <math.h>
#include <stdint.h>

typedef __hip_bfloat16 bf16;
typedef __attribute__((ext_vector_type(8))) __bf16 bf16x8;
typedef __attribute__((ext_vector_type(4))) float f32x4;

#define HDIM 768
#define MROWS 6144
#define NCHUNK 6

__device__ __forceinline__ float bf2f(unsigned int u) {
  union { unsigned int i; float f; } c; c.i = u << 16; return c.f;
}

__device__ __forceinline__ void gload16(const void* g, void* l) {
  __builtin_amdgcn_global_load_lds((const __attribute__((address_space(1))) void*)g,
                                   (__attribute__((address_space(3))) void*)l, 16, 0, 0);
}

// overflow-safe tanh-approx GELU (error ~1e-3 abs)
__device__ __forceinline__ float gelu_f(float v) {
  const float u2 = 1.5957691216057308f * (v + 0.044715f * v * v * v);
  const float e = __expf(u2);
  const float th = 1.f - 2.f / (e + 1.f);
  return 0.5f * v * (1.f + th);
}

// ---------------- weight transpose + f32->bf16 convert ----------------
__global__ __launch_bounds__(256) void wconv(
    const float* __restrict__ Wq, const float* __restrict__ Wk,
    const float* __restrict__ Wv, const float* __restrict__ Wo,
    const float* __restrict__ Wi, const float* __restrict__ Wo2,
    bf16* __restrict__ wt)
{
  __shared__ float tile[32][33];
  const int bid = blockIdx.x;
  const float* src; bf16* dst; int K, N, tIdx;
  if (bid < 2304) {
    int m = bid / 576; tIdx = bid % 576; K = 768; N = 768;
    src = (m == 0) ? Wq : (m == 1) ? Wk : (m == 2) ? Wv : Wo;
    dst = wt + (size_t)m * 589824;
  } else if (bid < 4608) {
    tIdx = bid - 2304; K = 768; N = 3072; src = Wi; dst = wt + 2359296;
  } else {
    tIdx = bid - 4608; K = 3072; N = 768; src = Wo2; dst = wt + 4718592;
  }
  const int tilesN = N >> 5;
  const int tn = tIdx % tilesN, tk = tIdx / tilesN;
  const int n0 = tn * 32, k0 = tk * 32;
  const int tx = threadIdx.x & 31, ty = threadIdx.x >> 5;
#pragma unroll
  for (int r = 0; r < 4; ++r)
    tile[ty + r * 8][tx] = src[(size_t)(k0 + ty + r * 8) * N + n0 + tx];
  __syncthreads();
#pragma unroll
  for (int r = 0; r < 4; ++r)
    dst[(size_t)(n0 + ty + r * 8) * K + k0 + tx] = __float2bfloat16(tile[tx][ty + r * 8]);
}

// ---------------- GEMM 256x256, 8 waves, BK=64, counted vmcnt, asm ds_read ----------------
// C = A[M,K](bf16) @ Bt[N,K]^T(bf16) + bias.
// LDS: A,B each [2 dbuf][2 khalf][256 x 32] = 128 KiB, 1 block/CU.
// Swizzle (R4-proven, 0 conflicts): byte bits 4,5 ^= row bits 1,2 — applied via
// pre-swizzled GLOBAL source (gload_lds dest linear) + swizzled asm ds_read addr.
// Frag reads are inline-asm ds_read_b128 so the compiler's waitcnt pass cannot
// insert vmcnt(0) for the gload_lds->LDS dependency (we order with our own
// counted vmcnt + barrier; lgkmcnt(0)+sched_barrier(0) before MFMA, rule 18).
__global__ __launch_bounds__(512, 2) void gemm256(
    const bf16* __restrict__ A, const bf16* __restrict__ Bt,
    void* __restrict__ out, const float* __restrict__ b0,
    const float* __restrict__ b1, const float* __restrict__ b2,
    int gx, int N, int K, int NT, int epi)
{
  __shared__ __align__(16) bf16 As[2][2][8192];   // [dbuf][khalf][256*32]
  __shared__ __align__(16) bf16 Bs[2][2][8192];

  const int nwg = gridDim.x;
  const int wg = blockIdx.x;
  const int L = (wg & 7) * (nwg >> 3) + (wg >> 3);   // XCD-contiguous (nwg%8==0)
  const int bx = L % gx, by = L / gx;
  const int m0 = by * 256, n0 = bx * 256;

  const int t = threadIdx.x;
  const int lane = t & 63;
  const int w = t >> 6;          // 0..7
  const int wr = w >> 2;         // 0..1  (M half)
  const int wc = w & 3;          // 0..3  (N quarter)
  const int fr = lane & 15;
  const int g = lane >> 4;       // 0..3

  f32x4 acc[8][4];
#pragma unroll
  for (int i = 0; i < 8; ++i)
#pragma unroll
    for (int j = 0; j < 4; ++j) acc[i][j] = (f32x4)0.f;

  // staging: thread t covers 16B slots {t, t+512} of each [256x32] k-half.
  // swizzle: within-row 16B-slot q ^= (row>>1)&3 on the GLOBAL source.
  const int r0 = t >> 2, q0 = t & 3;
  const int sq0 = q0 ^ ((r0 >> 1) & 3);
  const bf16* gA0 = A + (size_t)(m0 + r0) * K + sq0 * 8;
  const bf16* gB0 = Bt + (size_t)(n0 + r0) * K + sq0 * 8;
  const int dst0 = t * 16;

  // frag read byte offsets (within one [256][32] k-half buffer), swizzled
  unsigned offA[8], offB[4];
#pragma unroll
  for (int mf = 0; mf < 8; ++mf) {
    const int R = wr * 128 + mf * 16 + fr;
    offA[mf] = (unsigned)((R * 64 + g * 16) ^ (((R >> 1) & 3) << 4));
  }
#pragma unroll
  for (int nf = 0; nf < 4; ++nf) {
    const int R = wc * 64 + nf * 16 + fr;
    offB[nf] = (unsigned)((R * 64 + g * 16) ^ (((R >> 1) & 3) << 4));
  }
  const unsigned ldsA = (unsigned)(uintptr_t)&As[0][0][0];
  const unsigned ldsB = (unsigned)(uintptr_t)&Bs[0][0][0];

#define STAGE_A(KT, DB, KH) {                                              \
    const bf16* s_ = gA0 + (size_t)(KT) * 64 + (KH) * 32;                  \
    gload16(s_, (char*)As[DB][KH] + dst0);                                 \
    gload16(s_ + (size_t)128 * K, (char*)As[DB][KH] + dst0 + 8192); }
#define STAGE_B(KT, DB, KH) {                                              \
    const bf16* s_ = gB0 + (size_t)(KT) * 64 + (KH) * 32;                  \
    gload16(s_, (char*)Bs[DB][KH] + dst0);                                 \
    gload16(s_ + (size_t)128 * K, (char*)Bs[DB][KH] + dst0 + 8192); }

  // prologue: stage tile 0 (kh0, kh1) -> 8 outstanding
  STAGE_A(0, 0, 0) STAGE_B(0, 0, 0)
  STAGE_A(0, 0, 1) STAGE_B(0, 0, 1)

#define PHASE(KT, DB, KH) {                                                \
    const int pf_ = ((KT) + 1 < NT) ? (KT) + 1 : NT - 1;                   \
    STAGE_A(pf_, (DB) ^ 1, KH)                                             \
    STAGE_B(pf_, (DB) ^ 1, KH)                                             \
    asm volatile("s_waitcnt vmcnt(8)" ::: "memory");                       \
    __builtin_amdgcn_s_barrier();                                          \
    __builtin_amdgcn_sched_barrier(0);                                     \
    bf16x8 af[8], bfr[4];                                                  \
    const unsigned baA_ = ldsA + (DB) * 32768u + (KH) * 16384u;            \
    const unsigned baB_ = ldsB + (DB) * 32768u + (KH) * 16384u;            \
    _Pragma("unroll")                                                      \
    for (int mf = 0; mf < 8; ++mf)                                         \
      asm volatile("ds_read_b128 %0, %1" : "=v"(af[mf]) : "v"(baA_ + offA[mf])); \
    _Pragma("unroll")                                                      \
    for (int nf = 0; nf < 4; ++nf)                                         \
      asm volatile("ds_read_b128 %0, %1" : "=v"(bfr[nf]) : "v"(baB_ + offB[nf])); \
    asm volatile("s_waitcnt lgkmcnt(0)" ::: "memory");                     \
    __builtin_amdgcn_sched_barrier(0);                                     \
    __builtin_amdgcn_s_setprio(1);                                         \
    _Pragma("unroll")                                                      \
    for (int mf = 0; mf < 8; ++mf)                                         \
      _Pragma("unroll")                                                    \
      for (int nf = 0; nf < 4; ++nf)                                       \
        acc[mf][nf] = __builtin_amdgcn_mfma_f32_16x16x32_bf16(af[mf], bfr[nf], acc[mf][nf], 0, 0, 0); \
    __builtin_amdgcn_s_setprio(0);                                         \
  }

#pragma unroll 1
  for (int kt = 0; kt < NT; kt += 2) {   // NT even for all shapes (12 or 48)
    PHASE(kt, 0, 0)
    PHASE(kt, 0, 1)
    PHASE(kt + 1, 1, 0)
    PHASE(kt + 1, 1, 1)
  }
  asm volatile("s_waitcnt vmcnt(0)" ::: "memory");
#undef PHASE
#undef STAGE_A
#undef STAGE_B

  const int rr = (lane >> 4) * 4;
  const int cc0 = lane & 15;
  if (epi == 0) {
    const int mat = n0 / HDIM;                 // 768 % 256 == 0 -> uniform
    const float* bias = (mat == 0) ? b0 : (mat == 1) ? b1 : b2;
    const float qs = (mat == 0) ? 0.125f : 1.0f;
    bf16* dst = (bf16*)out + (size_t)mat * MROWS * HDIM;
    const int nl = n0 - mat * HDIM;
#pragma unroll
    for (int mf = 0; mf < 8; ++mf)
#pragma unroll
      for (int nf = 0; nf < 4; ++nf) {
        const int row = m0 + wr * 128 + mf * 16 + rr;
        const int col = nl + wc * 64 + nf * 16 + cc0;
        const float bv = bias[col];
#pragma unroll
        for (int r = 0; r < 4; ++r)
          dst[(size_t)(row + r) * HDIM + col] = __float2bfloat16((acc[mf][nf][r] + bv) * qs);
      }
  } else if (epi == 2) {
    bf16* dst = (bf16*)out;
#pragma unroll
    for (int mf = 0; mf < 8; ++mf)
#pragma unroll
      for (int nf = 0; nf < 4; ++nf) {
        const int row = m0 + wr * 128 + mf * 16 + rr;
        const int col = n0 + wc * 64 + nf * 16 + cc0;
        const float bv = b0[col];
#pragma unroll
        for (int r = 0; r < 4; ++r)
          dst[(size_t)(row + r) * N + col] = __float2bfloat16(gelu_f(acc[mf][nf][r] + bv));
      }
  } else {
    float* dst = (float*)out;
#pragma unroll
    for (int mf = 0; mf < 8; ++mf)
#pragma unroll
      for (int nf = 0; nf < 4; ++nf) {
        const int row = m0 + wr * 128 + mf * 16 + rr;
        const int col = n0 + wc * 64 + nf * 16 + cc0;
        const float bv = b0[col];
#pragma unroll
        for (int r = 0; r < 4; ++r)
          dst[(size_t)(row + r) * N + col] = acc[mf][nf][r] + bv;
      }
  }
}

// ---------------- MFMA sliding-window attention ----------------
__global__ __launch_bounds__(256) void attn_mfma(
    const bf16* __restrict__ qkv, bf16* __restrict__ attb)
{
  const int c = blockIdx.x, h = blockIdx.y, b = blockIdx.z;
  __shared__ unsigned int Vtw[64 * 64];
  __shared__ __align__(16) bf16 Pl[4][32 * 40];
  const int t = threadIdx.x;
  const int lane = t & 63;
  const int w = t >> 6;
  const int fr = lane & 15;
  const int g = lane >> 4;
  const bf16* Km = qkv + (size_t)4718592;
  const bf16* Vm = qkv + (size_t)9437184;
  const size_t qrow0 = (size_t)(b * 768 + c * 128);

  bf16x8 qf[2][2];
#pragma unroll
  for (int nt = 0; nt < 2; ++nt)
#pragma unroll
    for (int ks = 0; ks < 2; ++ks)
      qf[nt][ks] = *(const bf16x8*)(qkv + (qrow0 + w * 32 + nt * 16 + fr) * HDIM + h * 64 + ks * 32 + g * 8);

  f32x4 oacc[4][2];
#pragma unroll
  for (int i = 0; i < 4; ++i) { oacc[i][0] = (f32x4)0.f; oacc[i][1] = (f32x4)0.f; }
  float mrun[2] = {-1e30f, -1e30f};
  float lrun[2] = {0.f, 0.f};

#pragma unroll 1
  for (int cc = c - 1; cc <= c + 1; ++cc) {
    if (cc < 0 || cc >= NCHUNK) continue;
    __syncthreads();
    {
      const int d0 = (t & 7) * 8;
#pragma unroll
      for (int half = 0; half < 2; ++half) {
        const int kp2 = (t >> 3) + half * 32;
        const bf16* vr = Vm + ((size_t)(b * 768 + cc * 128) + kp2 * 2) * HDIM + h * 64 + d0;
        uint4 r0 = *(const uint4*)vr;
        uint4 r1 = *(const uint4*)(vr + HDIM);
        unsigned int a0[4] = {r0.x, r0.y, r0.z, r0.w};
        unsigned int a1[4] = {r1.x, r1.y, r1.z, r1.w};
#pragma unroll
        for (int e = 0; e < 8; ++e) {
          const int d = d0 + e;
          unsigned int lo = (a0[e >> 1] >> ((e & 1) * 16)) & 0xffffu;
          unsigned int hi = (a1[e >> 1] >> ((e & 1) * 16)) & 0xffffu;
          unsigned int byteoff = (unsigned int)(d * 256 + kp2 * 4);
          byteoff ^= ((((d >> 3) ^ d) & 7) << 4);
          Vtw[byteoff >> 2] = lo | (hi << 16);
        }
      }
    }
    __syncthreads();
    const int mode = (cc < c) ? 0 : (cc == c ? 1 : 2);
    const bf16* Kc = Km + ((size_t)(b * 768 + cc * 128)) * HDIM + h * 64;

#pragma unroll 1
    for (int kb = 0; kb < 4; ++kb) {
      f32x4 sacc[2][2];
      sacc[0][0] = sacc[0][1] = sacc[1][0] = sacc[1][1] = (f32x4)0.f;
#pragma unroll
      for (int ks = 0; ks < 2; ++ks)
#pragma unroll
        for (int mt = 0; mt < 2; ++mt) {
          bf16x8 kf = *(const bf16x8*)(Kc + (size_t)(kb * 32 + mt * 16 + fr) * HDIM + ks * 32 + g * 8);
          sacc[mt][0] = __builtin_amdgcn_mfma_f32_16x16x32_bf16(kf, qf[0][ks], sacc[mt][0], 0, 0, 0);
          sacc[mt][1] = __builtin_amdgcn_mfma_f32_16x16x32_bf16(kf, qf[1][ks], sacc[mt][1], 0, 0, 0);
        }
#pragma unroll
      for (int nt = 0; nt < 2; ++nt) {
        const int iq = w * 32 + nt * 16 + fr;
        float pm = -1e30f;
#pragma unroll
        for (int mt = 0; mt < 2; ++mt)
#pragma unroll
          for (int r = 0; r < 4; ++r) {
            const int j = kb * 32 + mt * 16 + g * 4 + r;
            const bool valid = (mode == 1) || (mode == 0 ? (j >= iq) : (j <= iq));
            const float sv = valid ? sacc[mt][nt][r] : -1e30f;
            sacc[mt][nt][r] = sv;
            pm = fmaxf(pm, sv);
          }
        pm = fmaxf(pm, __shfl_xor(pm, 16));
        pm = fmaxf(pm, __shfl_xor(pm, 32));
        const float mnew = fmaxf(fmaxf(mrun[nt], pm), -1e20f);
        const float sc = __expf(mrun[nt] - mnew);
        mrun[nt] = mnew;
        lrun[nt] *= sc;
#pragma unroll
        for (int mt = 0; mt < 4; ++mt) oacc[mt][nt] *= sc;
        float ps = 0.f;
#pragma unroll
        for (int mt = 0; mt < 2; ++mt) {
          union { bf16 hh[4]; uint2 uu; } pk;
#pragma unroll
          for (int r = 0; r < 4; ++r) {
            const float p = __expf(sacc[mt][nt][r] - mnew);
            ps += p;
            pk.hh[r] = __float2bfloat16(p);
          }
          *(uint2*)(&Pl[w][(nt * 16 + fr) * 40 + mt * 16 + g * 4]) = pk.uu;
        }
        ps += __shfl_xor(ps, 16);
        ps += __shfl_xor(ps, 32);
        lrun[nt] += ps;
      }
      bf16x8 bpf[2];
#pragma unroll
      for (int nt = 0; nt < 2; ++nt)
        bpf[nt] = *(const bf16x8*)(&Pl[w][(nt * 16 + fr) * 40 + g * 8]);
#pragma unroll
      for (int mt = 0; mt < 4; ++mt) {
        const int d = mt * 16 + fr;
        unsigned int byteoff = (unsigned int)(d * 256 + kb * 64 + g * 16);
        byteoff ^= ((((d >> 3) ^ d) & 7) << 4);
        bf16x8 vf = *(const bf16x8*)((const char*)Vtw + byteoff);
        oacc[mt][0] = __builtin_amdgcn_mfma_f32_16x16x32_bf16(vf, bpf[0], oacc[mt][0], 0, 0, 0);
        oacc[mt][1] = __builtin_amdgcn_mfma_f32_16x16x32_bf16(vf, bpf[1], oacc[mt][1], 0, 0, 0);
      }
    }
  }
#pragma unroll
  for (int nt = 0; nt < 2; ++nt) {
    const float rl = 1.f / lrun[nt];
    bf16* orow = attb + (qrow0 + w * 32 + nt * 16 + fr) * HDIM + h * 64;
#pragma unroll
    for (int mt = 0; mt < 4; ++mt) {
      union { bf16 hh[4]; uint2 uu; } ok;
#pragma unroll
      for (int r = 0; r < 4; ++r) ok.hh[r] = __float2bfloat16(oacc[mt][nt][r] * rl);
      *(uint2*)(orow + mt * 16 + g * 4) = ok.uu;
    }
  }
}

// ---------------- LayerNorm kernels ----------------
__device__ __forceinline__ void blk_reduce2(float& s1, float& s2) {
#pragma unroll
  for (int o = 32; o > 0; o >>= 1) { s1 += __shfl_xor(s1, o); s2 += __shfl_xor(s2, o); }
  __shared__ float red[8];
  const int w = threadIdx.x >> 6;
  if ((threadIdx.x & 63) == 0) { red[w] = s1; red[4 + w] = s2; }
  __syncthreads();
  s1 = red[0] + red[1] + red[2] + red[3];
  s2 = red[4] + red[5] + red[6] + red[7];
}

__global__ __launch_bounds__(256) void embed_ln(
    const float* __restrict__ emb, const float* __restrict__ pos,
    const float* __restrict__ tte, const float* __restrict__ g,
    const float* __restrict__ bt, float* __restrict__ x, bf16* __restrict__ xb)
{
  const int row = blockIdx.x;
  const int s = row % 768;
  const int t = threadIdx.x;
  const size_t base = (size_t)row * HDIM;
  const size_t pbase = (size_t)(s + 2) * HDIM;
  float v[3];
#pragma unroll
  for (int i = 0; i < 3; ++i) {
    const int idx = t + i * 256;
    v[i] = emb[base + idx] + pos[pbase + idx] + tte[idx];
  }
  float s1 = v[0] + v[1] + v[2];
  float s2 = v[0]*v[0] + v[1]*v[1] + v[2]*v[2];
  blk_reduce2(s1, s2);
  const float mu = s1 * (1.f / 768.f);
  const float var = s2 * (1.f / 768.f) - mu * mu;
  const float inv = rsqrtf(var + 1e-12f);
#pragma unroll
  for (int i = 0; i < 3; ++i) {
    const int idx = t + i * 256;
    const float o = (v[i] - mu) * inv * g[idx] + bt[idx];
    x[base + idx] = o;
    xb[base + idx] = __float2bfloat16(o);
  }
}

__global__ __launch_bounds__(256) void add_ln(
    const float* __restrict__ tmp, float* __restrict__ x, bf16* __restrict__ xb,
    const float* __restrict__ g, const float* __restrict__ bt)
{
  const int row = blockIdx.x;
  const int t = threadIdx.x;
  const size_t base = (size_t)row * HDIM;
  float v[3];
#pragma unroll
  for (int i = 0; i < 3; ++i) {
    const int idx = t + i * 256;
    v[i] = x[base + idx] + tmp[base + idx];
  }
  float s1 = v[0] + v[1] + v[2];
  float s2 = v[0]*v[0] + v[1]*v[1] + v[2]*v[2];
  blk_reduce2(s1, s2);
  const float mu = s1 * (1.f / 768.f);
  const float var = s2 * (1.f / 768.f) - mu * mu;
  const float inv = rsqrtf(var + 1e-12f);
#pragma unroll
  for (int i = 0; i < 3; ++i) {
    const int idx = t + i * 256;
    const float o = (v[i] - mu) * inv * g[idx] + bt[idx];
    x[base + idx] = o;
    xb[base + idx] = __float2bfloat16(o);
  }
}

// ---------------- gate ----------------
__global__ __launch_bounds__(256) void gate_kernel(
    const float* __restrict__ x, const float* __restrict__ gw,
    const float* __restrict__ gb, float* __restrict__ out)
{
  const int row = blockIdx.x * 4 + (threadIdx.x >> 6);
  const int lane = threadIdx.x & 63;
  const float* xr = x + (size_t)row * HDIM;
  float s = 0.f;
#pragma unroll
  for (int i = 0; i < 12; ++i) s += xr[lane + i * 64] * gw[lane + i * 64];
#pragma unroll
  for (int o = 32; o > 0; o >>= 1) s += __shfl_xor(s, o);
  if (lane == 0) out[row] = s + gb[0];
}

// ---------------- host ----------------
extern "C" void kernel_launch(void* const* d_in, const int* in_sizes, int n_in,
                              void* d_out, int out_size, void* d_ws, size_t ws_size,
                              hipStream_t stream)
{
  const float* emb = (const float*)d_in[0];
  const float* pos = (const float*)d_in[2];
  const float* tte = (const float*)d_in[3];
  const float* eg  = (const float*)d_in[4];
  const float* eb  = (const float*)d_in[5];
  const float* Wq  = (const float*)d_in[6];
  const float* bq  = (const float*)d_in[7];
  const float* Wk  = (const float*)d_in[8];
  const float* bk  = (const float*)d_in[9];
  const float* Wv  = (const float*)d_in[10];
  const float* bv  = (const float*)d_in[11];
  const float* Wo  = (const float*)d_in[12];
  const float* bo  = (const float*)d_in[13];
  const float* g1  = (const float*)d_in[14];
  const float* be1 = (const float*)d_in[15];
  const float* Wi  = (const float*)d_in[16];
  const float* bi  = (const float*)d_in[17];
  const float* Wo2 = (const float*)d_in[18];
  const float* bo2 = (const float*)d_in[19];
  const float* g2  = (const float*)d_in[20];
  const float* be2 = (const float*)d_in[21];
  const float* gw  = (const float*)d_in[22];
  const float* gb  = (const float*)d_in[23];

  char* wsp = (char*)d_ws;
  bf16* wt   = (bf16*)wsp;
  bf16* xb   = (bf16*)(wsp + 14155776);
  bf16* qkvb = (bf16*)(wsp + 23592960);
  float* tmp = (float*)(wsp + 61341696);
  bf16* attb = qkvb + (size_t)3 * 4718592;
  bf16* ffb  = qkvb;                 // alias: q/k/v/att dead when FFN1 runs
  float* x   = (float*)d_out;        // f32 residual stream lives in d_out
  float* gate = x + 4718592;

  embed_ln<<<6144, 256, 0, stream>>>(emb, pos, tte, eg, eb, x, xb);

  for (int l = 0; l < 12; ++l) {
    wconv<<<6912, 256, 0, stream>>>(Wq + (size_t)l * 589824, Wk + (size_t)l * 589824,
                                    Wv + (size_t)l * 589824, Wo + (size_t)l * 589824,
                                    Wi + (size_t)l * 2359296, Wo2 + (size_t)l * 2359296, wt);
    // QKV: M=6144 N=2304 K=768 -> 24x9 = 216 blocks
    gemm256<<<216, 512, 0, stream>>>(xb, wt, qkvb,
        bq + l * 768, bk + l * 768, bv + l * 768, 9, 2304, 768, 12, 0);
    attn_mfma<<<dim3(6, 12, 8), 256, 0, stream>>>(qkvb, attb);
    // OProj: N=768 K=768 -> 24x3 = 72 blocks
    gemm256<<<72, 512, 0, stream>>>(attb, wt + 1769472, tmp,
        bo + l * 768, nullptr, nullptr, 3, 768, 768, 12, 3);
    add_ln<<<6144, 256, 0, stream>>>(tmp, x, xb, g1 + l * 768, be1 + l * 768);
    // FFN1: N=3072 K=768 -> 24x12 = 288 blocks
    gemm256<<<288, 512, 0, stream>>>(xb, wt + 2359296, ffb,
        bi + l * 3072, nullptr, nullptr, 12, 3072, 768, 12, 2);
    // FFN2: N=768 K=3072 -> 24x3 = 72 blocks
    gemm256<<<72, 512, 0, stream>>>(ffb, wt + 4718592, tmp,
        bo2 + l * 768, nullptr, nullptr, 3, 768, 3072, 48, 3);
    add_ln<<<6144, 256, 0, stream>>>(tmp, x, xb, g2 + l * 768, be2 + l * 768);
  }

  gate_kernel<<<1536, 256, 0, stream>>>(x, gw, gb, gate);
}

// Round 7
// 3217.808 us; speedup vs baseline: 1.0781x; 1.0021x over previous
//
#include <hip/hip_runtime.h>
#include <hip/hip_bf16.h>
#include <math.h>
#include <stdint.h>

typedef __hip_bfloat16 bf16;
typedef __attribute__((ext_vector_type(8))) __bf16 bf16x8;
typedef __attribute__((ext_vector_type(4))) float f32x4;

#define HDIM 768
#define MROWS 6144
#define NCHUNK 6

__device__ __forceinline__ float bf2f(unsigned int u) {
  union { unsigned int i; float f; } c; c.i = u << 16; return c.f;
}

__device__ __forceinline__ void gload16(const void* g, void* l) {
  __builtin_amdgcn_global_load_lds((const __attribute__((address_space(1))) void*)g,
                                   (__attribute__((address_space(3))) void*)l, 16, 0, 0);
}

// overflow-safe tanh-approx GELU (error ~1e-3 abs)
__device__ __forceinline__ float gelu_f(float v) {
  const float u2 = 1.5957691216057308f * (v + 0.044715f * v * v * v);
  const float e = __expf(u2);
  const float th = 1.f - 2.f / (e + 1.f);
  return 0.5f * v * (1.f + th);
}

// ---------------- weight transpose + f32->bf16 convert ----------------
__global__ __launch_bounds__(256) void wconv(
    const float* __restrict__ Wq, const float* __restrict__ Wk,
    const float* __restrict__ Wv, const float* __restrict__ Wo,
    const float* __restrict__ Wi, const float* __restrict__ Wo2,
    bf16* __restrict__ wt)
{
  __shared__ float tile[32][33];
  const int bid = blockIdx.x;
  const float* src; bf16* dst; int K, N, tIdx;
  if (bid < 2304) {
    int m = bid / 576; tIdx = bid % 576; K = 768; N = 768;
    src = (m == 0) ? Wq : (m == 1) ? Wk : (m == 2) ? Wv : Wo;
    dst = wt + (size_t)m * 589824;
  } else if (bid < 4608) {
    tIdx = bid - 2304; K = 768; N = 3072; src = Wi; dst = wt + 2359296;
  } else {
    tIdx = bid - 4608; K = 3072; N = 768; src = Wo2; dst = wt + 4718592;
  }
  const int tilesN = N >> 5;
  const int tn = tIdx % tilesN, tk = tIdx / tilesN;
  const int n0 = tn * 32, k0 = tk * 32;
  const int tx = threadIdx.x & 31, ty = threadIdx.x >> 5;
#pragma unroll
  for (int r = 0; r < 4; ++r)
    tile[ty + r * 8][tx] = src[(size_t)(k0 + ty + r * 8) * N + n0 + tx];
  __syncthreads();
#pragma unroll
  for (int r = 0; r < 4; ++r)
    dst[(size_t)(n0 + ty + r * 8) * K + k0 + tx] = __float2bfloat16(tile[tx][ty + r * 8]);
}

// ---------------- GEMM 256x256, 8 waves, BK=64, m201-style phase schedule ----------------
// C = A[M,K](bf16) @ Bt[N,K]^T(bf16) + bias.
// LDS: A,B each [2 dbuf][2 khalf][256 x 32] = 128 KiB, 1 block/CU.
// Phase: {12 asm ds_read (cur,kh) || 4 gload_lds (next tile, same kh)} ->
//        lgkmcnt(0) -> 32 MFMA -> vmcnt(4) -> s_barrier.
// vmcnt(4) drains exactly the k-half unit the NEXT phase reads (issued 2 phases
// earlier); buffer being overwritten was last read 2 barriers ago (WAR-safe).
// Swizzle (0 conflicts, R4/R6-proven): 16B-slot q ^= (row>>1)&3, both sides.
__global__ __launch_bounds__(512, 2) void gemm256(
    const bf16* __restrict__ A, const bf16* __restrict__ Bt,
    void* __restrict__ out, const float* __restrict__ b0,
    const float* __restrict__ b1, const float* __restrict__ b2,
    int gx, int N, int K, int NT, int epi)
{
  __shared__ __align__(16) bf16 As[2][2][8192];   // [dbuf][khalf][256*32]
  __shared__ __align__(16) bf16 Bs[2][2][8192];

  const int nwg = gridDim.x;
  const int wg = blockIdx.x;
  const int L = (wg & 7) * (nwg >> 3) + (wg >> 3);   // XCD-contiguous (nwg%8==0)
  const int bx = L % gx, by = L / gx;
  const int m0 = by * 256, n0 = bx * 256;

  const int t = threadIdx.x;
  const int lane = t & 63;
  const int w = t >> 6;          // 0..7
  const int wr = w >> 2;         // 0..1  (M half)
  const int wc = w & 3;          // 0..3  (N quarter)
  const int fr = lane & 15;
  const int g = lane >> 4;       // 0..3

  f32x4 acc[8][4];
#pragma unroll
  for (int i = 0; i < 8; ++i)
#pragma unroll
    for (int j = 0; j < 4; ++j) acc[i][j] = (f32x4)0.f;

  // staging: per k-half unit [256 rows x 32 K] = 1024 16B-slots; thread t covers
  // slots {t, t+512}. slot -> row = s>>2 (+128 for 2nd), q = s&3, swizzled source.
  const int r0 = t >> 2, q0 = t & 3;
  const int sq0 = q0 ^ ((r0 >> 1) & 3);            // ((r0+128)>>1)&3 == same
  const bf16* gA0 = A + (size_t)(m0 + r0) * K + sq0 * 8;
  const bf16* gB0 = Bt + (size_t)(n0 + r0) * K + sq0 * 8;
  const int dst0 = t * 16;

  // frag read byte offsets within one [256][32] k-half buffer, swizzled
  unsigned offA[8], offB[4];
#pragma unroll
  for (int mf = 0; mf < 8; ++mf) {
    const int R = wr * 128 + mf * 16 + fr;
    offA[mf] = (unsigned)((R * 64 + g * 16) ^ (((R >> 1) & 3) << 4));
  }
#pragma unroll
  for (int nf = 0; nf < 4; ++nf) {
    const int R = wc * 64 + nf * 16 + fr;
    offB[nf] = (unsigned)((R * 64 + g * 16) ^ (((R >> 1) & 3) << 4));
  }
  const unsigned ldsA = (unsigned)(uintptr_t)&As[0][0][0];
  const unsigned ldsB = (unsigned)(uintptr_t)&Bs[0][0][0];

  // stage one k-half unit of tile KT into [DB][KH]: 2A + 2B loads
#define STAGE(KT, DB, KH) {                                                \
    const bf16* a_ = gA0 + (size_t)(KT) * 64 + (KH) * 32;                  \
    const bf16* b_ = gB0 + (size_t)(KT) * 64 + (KH) * 32;                  \
    gload16(a_, (char*)As[DB][KH] + dst0);                                 \
    gload16(a_ + (size_t)128 * K, (char*)As[DB][KH] + dst0 + 8192);        \
    gload16(b_, (char*)Bs[DB][KH] + dst0);                                 \
    gload16(b_ + (size_t)128 * K, (char*)Bs[DB][KH] + dst0 + 8192); }

  // prologue: stage tile 0 (kh0, kh1); drain kh0 (leave kh1's 4 in flight)
  STAGE(0, 0, 0)
  STAGE(0, 0, 1)
  asm volatile("s_waitcnt vmcnt(4)" ::: "memory");
  __builtin_amdgcn_s_barrier();

#define PHASE(KT, KH, DB) {                                                \
    bf16x8 af[8], bfr[4];                                                  \
    const unsigned baA_ = ldsA + (DB) * 32768u + (KH) * 16384u;            \
    const unsigned baB_ = ldsB + (DB) * 32768u + (KH) * 16384u;            \
    _Pragma("unroll")                                                      \
    for (int mf = 0; mf < 8; ++mf)                                         \
      asm volatile("ds_read_b128 %0, %1" : "=v"(af[mf]) : "v"(baA_ + offA[mf])); \
    _Pragma("unroll")                                                      \
    for (int nf = 0; nf < 4; ++nf)                                         \
      asm volatile("ds_read_b128 %0, %1" : "=v"(bfr[nf]) : "v"(baB_ + offB[nf])); \
    const int pf_ = ((KT) + 1 < NT) ? (KT) + 1 : (KT);                     \
    STAGE(pf_, (DB) ^ 1, KH)                                               \
    asm volatile("s_waitcnt lgkmcnt(0)" ::: "memory");                     \
    __builtin_amdgcn_sched_barrier(0);                                     \
    __builtin_amdgcn_s_setprio(1);                                         \
    _Pragma("unroll")                                                      \
    for (int mf = 0; mf < 8; ++mf)                                         \
      _Pragma("unroll")                                                    \
      for (int nf = 0; nf < 4; ++nf)                                       \
        acc[mf][nf] = __builtin_amdgcn_mfma_f32_16x16x32_bf16(af[mf], bfr[nf], acc[mf][nf], 0, 0, 0); \
    __builtin_amdgcn_s_setprio(0);                                         \
    asm volatile("s_waitcnt vmcnt(4)" ::: "memory");                       \
    __builtin_amdgcn_s_barrier();                                          \
  }

#pragma unroll 1
  for (int kt = 0; kt < NT; kt += 2) {   // NT even for all shapes (12 or 48)
    PHASE(kt, 0, 0)
    PHASE(kt, 1, 0)
    PHASE(kt + 1, 0, 1)
    PHASE(kt + 1, 1, 1)
  }
  asm volatile("s_waitcnt vmcnt(0)" ::: "memory");
#undef PHASE
#undef STAGE

  const int rr = (lane >> 4) * 4;
  const int cc0 = lane & 15;
  if (epi == 0) {
    const int mat = n0 / HDIM;                 // uniform per block (256 | 768 tiles)
    const float* bias = (mat == 0) ? b0 : (mat == 1) ? b1 : b2;
    const float qs = (mat == 0) ? 0.125f : 1.0f;
    bf16* dst = (bf16*)out + (size_t)mat * MROWS * HDIM;
    const int nl = n0 - mat * HDIM;
#pragma unroll
    for (int mf = 0; mf < 8; ++mf)
#pragma unroll
      for (int nf = 0; nf < 4; ++nf) {
        const int row = m0 + wr * 128 + mf * 16 + rr;
        const int col = nl + wc * 64 + nf * 16 + cc0;
        const float bv = bias[col];
#pragma unroll
        for (int r = 0; r < 4; ++r)
          dst[(size_t)(row + r) * HDIM + col] = __float2bfloat16((acc[mf][nf][r] + bv) * qs);
      }
  } else if (epi == 2) {
    bf16* dst = (bf16*)out;
#pragma unroll
    for (int mf = 0; mf < 8; ++mf)
#pragma unroll
      for (int nf = 0; nf < 4; ++nf) {
        const int row = m0 + wr * 128 + mf * 16 + rr;
        const int col = n0 + wc * 64 + nf * 16 + cc0;
        const float bv = b0[col];
#pragma unroll
        for (int r = 0; r < 4; ++r)
          dst[(size_t)(row + r) * N + col] = __float2bfloat16(gelu_f(acc[mf][nf][r] + bv));
      }
  } else {
    float* dst = (float*)out;
#pragma unroll
    for (int mf = 0; mf < 8; ++mf)
#pragma unroll
      for (int nf = 0; nf < 4; ++nf) {
        const int row = m0 + wr * 128 + mf * 16 + rr;
        const int col = n0 + wc * 64 + nf * 16 + cc0;
        const float bv = b0[col];
#pragma unroll
        for (int r = 0; r < 4; ++r)
          dst[(size_t)(row + r) * N + col] = acc[mf][nf][r] + bv;
      }
  }
}

// ---------------- MFMA sliding-window attention ----------------
__global__ __launch_bounds__(256) void attn_mfma(
    const bf16* __restrict__ qkv, bf16* __restrict__ attb)
{
  const int c = blockIdx.x, h = blockIdx.y, b = blockIdx.z;
  __shared__ unsigned int Vtw[64 * 64];
  __shared__ __align__(16) bf16 Pl[4][32 * 40];
  const int t = threadIdx.x;
  const int lane = t & 63;
  const int w = t >> 6;
  const int fr = lane & 15;
  const int g = lane >> 4;
  const bf16* Km = qkv + (size_t)4718592;
  const bf16* Vm = qkv + (size_t)9437184;
  const size_t qrow0 = (size_t)(b * 768 + c * 128);

  bf16x8 qf[2][2];
#pragma unroll
  for (int nt = 0; nt < 2; ++nt)
#pragma unroll
    for (int ks = 0; ks < 2; ++ks)
      qf[nt][ks] = *(const bf16x8*)(qkv + (qrow0 + w * 32 + nt * 16 + fr) * HDIM + h * 64 + ks * 32 + g * 8);

  f32x4 oacc[4][2];
#pragma unroll
  for (int i = 0; i < 4; ++i) { oacc[i][0] = (f32x4)0.f; oacc[i][1] = (f32x4)0.f; }
  float mrun[2] = {-1e30f, -1e30f};
  float lrun[2] = {0.f, 0.f};

#pragma unroll 1
  for (int cc = c - 1; cc <= c + 1; ++cc) {
    if (cc < 0 || cc >= NCHUNK) continue;
    __syncthreads();
    {
      const int d0 = (t & 7) * 8;
#pragma unroll
      for (int half = 0; half < 2; ++half) {
        const int kp2 = (t >> 3) + half * 32;
        const bf16* vr = Vm + ((size_t)(b * 768 + cc * 128) + kp2 * 2) * HDIM + h * 64 + d0;
        uint4 r0 = *(const uint4*)vr;
        uint4 r1 = *(const uint4*)(vr + HDIM);
        unsigned int a0[4] = {r0.x, r0.y, r0.z, r0.w};
        unsigned int a1[4] = {r1.x, r1.y, r1.z, r1.w};
#pragma unroll
        for (int e = 0; e < 8; ++e) {
          const int d = d0 + e;
          unsigned int lo = (a0[e >> 1] >> ((e & 1) * 16)) & 0xffffu;
          unsigned int hi = (a1[e >> 1] >> ((e & 1) * 16)) & 0xffffu;
          unsigned int byteoff = (unsigned int)(d * 256 + kp2 * 4);
          byteoff ^= ((((d >> 3) ^ d) & 7) << 4);
          Vtw[byteoff >> 2] = lo | (hi << 16);
        }
      }
    }
    __syncthreads();
    const int mode = (cc < c) ? 0 : (cc == c ? 1 : 2);
    const bf16* Kc = Km + ((size_t)(b * 768 + cc * 128)) * HDIM + h * 64;

#pragma unroll 1
    for (int kb = 0; kb < 4; ++kb) {
      f32x4 sacc[2][2];
      sacc[0][0] = sacc[0][1] = sacc[1][0] = sacc[1][1] = (f32x4)0.f;
#pragma unroll
      for (int ks = 0; ks < 2; ++ks)
#pragma unroll
        for (int mt = 0; mt < 2; ++mt) {
          bf16x8 kf = *(const bf16x8*)(Kc + (size_t)(kb * 32 + mt * 16 + fr) * HDIM + ks * 32 + g * 8);
          sacc[mt][0] = __builtin_amdgcn_mfma_f32_16x16x32_bf16(kf, qf[0][ks], sacc[mt][0], 0, 0, 0);
          sacc[mt][1] = __builtin_amdgcn_mfma_f32_16x16x32_bf16(kf, qf[1][ks], sacc[mt][1], 0, 0, 0);
        }
#pragma unroll
      for (int nt = 0; nt < 2; ++nt) {
        const int iq = w * 32 + nt * 16 + fr;
        float pm = -1e30f;
#pragma unroll
        for (int mt = 0; mt < 2; ++mt)
#pragma unroll
          for (int r = 0; r < 4; ++r) {
            const int j = kb * 32 + mt * 16 + g * 4 + r;
            const bool valid = (mode == 1) || (mode == 0 ? (j >= iq) : (j <= iq));
            const float sv = valid ? sacc[mt][nt][r] : -1e30f;
            sacc[mt][nt][r] = sv;
            pm = fmaxf(pm, sv);
          }
        pm = fmaxf(pm, __shfl_xor(pm, 16));
        pm = fmaxf(pm, __shfl_xor(pm, 32));
        const float mnew = fmaxf(fmaxf(mrun[nt], pm), -1e20f);
        const float sc = __expf(mrun[nt] - mnew);
        mrun[nt] = mnew;
        lrun[nt] *= sc;
#pragma unroll
        for (int mt = 0; mt < 4; ++mt) oacc[mt][nt] *= sc;
        float ps = 0.f;
#pragma unroll
        for (int mt = 0; mt < 2; ++mt) {
          union { bf16 hh[4]; uint2 uu; } pk;
#pragma unroll
          for (int r = 0; r < 4; ++r) {
            const float p = __expf(sacc[mt][nt][r] - mnew);
            ps += p;
            pk.hh[r] = __float2bfloat16(p);
          }
          *(uint2*)(&Pl[w][(nt * 16 + fr) * 40 + mt * 16 + g * 4]) = pk.uu;
        }
        ps += __shfl_xor(ps, 16);
        ps += __shfl_xor(ps, 32);
        lrun[nt] += ps;
      }
      bf16x8 bpf[2];
#pragma unroll
      for (int nt = 0; nt < 2; ++nt)
        bpf[nt] = *(const bf16x8*)(&Pl[w][(nt * 16 + fr) * 40 + g * 8]);
#pragma unroll
      for (int mt = 0; mt < 4; ++mt) {
        const int d = mt * 16 + fr;
        unsigned int byteoff = (unsigned int)(d * 256 + kb * 64 + g * 16);
        byteoff ^= ((((d >> 3) ^ d) & 7) << 4);
        bf16x8 vf = *(const bf16x8*)((const char*)Vtw + byteoff);
        oacc[mt][0] = __builtin_amdgcn_mfma_f32_16x16x32_bf16(vf, bpf[0], oacc[mt][0], 0, 0, 0);
        oacc[mt][1] = __builtin_amdgcn_mfma_f32_16x16x32_bf16(vf, bpf[1], oacc[mt][1], 0, 0, 0);
      }
    }
  }
#pragma unroll
  for (int nt = 0; nt < 2; ++nt) {
    const float rl = 1.f / lrun[nt];
    bf16* orow = attb + (qrow0 + w * 32 + nt * 16 + fr) * HDIM + h * 64;
#pragma unroll
    for (int mt = 0; mt < 4; ++mt) {
      union { bf16 hh[4]; uint2 uu; } ok;
#pragma unroll
      for (int r = 0; r < 4; ++r) ok.hh[r] = __float2bfloat16(oacc[mt][nt][r] * rl);
      *(uint2*)(orow + mt * 16 + g * 4) = ok.uu;
    }
  }
}

// ---------------- LayerNorm kernels ----------------
__device__ __forceinline__ void blk_reduce2(float& s1, float& s2) {
#pragma unroll
  for (int o = 32; o > 0; o >>= 1) { s1 += __shfl_xor(s1, o); s2 += __shfl_xor(s2, o); }
  __shared__ float red[8];
  const int w = threadIdx.x >> 6;
  if ((threadIdx.x & 63) == 0) { red[w] = s1; red[4 + w] = s2; }
  __syncthreads();
  s1 = red[0] + red[1] + red[2] + red[3];
  s2 = red[4] + red[5] + red[6] + red[7];
}

__global__ __launch_bounds__(256) void embed_ln(
    const float* __restrict__ emb, const float* __restrict__ pos,
    const float* __restrict__ tte, const float* __restrict__ g,
    const float* __restrict__ bt, float* __restrict__ x, bf16* __restrict__ xb)
{
  const int row = blockIdx.x;
  const int s = row % 768;
  const int t = threadIdx.x;
  const size_t base = (size_t)row * HDIM;
  const size_t pbase = (size_t)(s + 2) * HDIM;
  float v[3];
#pragma unroll
  for (int i = 0; i < 3; ++i) {
    const int idx = t + i * 256;
    v[i] = emb[base + idx] + pos[pbase + idx] + tte[idx];
  }
  float s1 = v[0] + v[1] + v[2];
  float s2 = v[0]*v[0] + v[1]*v[1] + v[2]*v[2];
  blk_reduce2(s1, s2);
  const float mu = s1 * (1.f / 768.f);
  const float var = s2 * (1.f / 768.f) - mu * mu;
  const float inv = rsqrtf(var + 1e-12f);
#pragma unroll
  for (int i = 0; i < 3; ++i) {
    const int idx = t + i * 256;
    const float o = (v[i] - mu) * inv * g[idx] + bt[idx];
    x[base + idx] = o;
    xb[base + idx] = __float2bfloat16(o);
  }
}

__global__ __launch_bounds__(256) void add_ln(
    const float* __restrict__ tmp, float* __restrict__ x, bf16* __restrict__ xb,
    const float* __restrict__ g, const float* __restrict__ bt)
{
  const int row = blockIdx.x;
  const int t = threadIdx.x;
  const size_t base = (size_t)row * HDIM;
  float v[3];
#pragma unroll
  for (int i = 0; i < 3; ++i) {
    const int idx = t + i * 256;
    v[i] = x[base + idx] + tmp[base + idx];
  }
  float s1 = v[0] + v[1] + v[2];
  float s2 = v[0]*v[0] + v[1]*v[1] + v[2]*v[2];
  blk_reduce2(s1, s2);
  const float mu = s1 * (1.f / 768.f);
  const float var = s2 * (1.f / 768.f) - mu * mu;
  const float inv = rsqrtf(var + 1e-12f);
#pragma unroll
  for (int i = 0; i < 3; ++i) {
    const int idx = t + i * 256;
    const float o = (v[i] - mu) * inv * g[idx] + bt[idx];
    x[base + idx] = o;
    xb[base + idx] = __float2bfloat16(o);
  }
}

// ---------------- gate ----------------
__global__ __launch_bounds__(256) void gate_kernel(
    const float* __restrict__ x, const float* __restrict__ gw,
    const float* __restrict__ gb, float* __restrict__ out)
{
  const int row = blockIdx.x * 4 + (threadIdx.x >> 6);
  const int lane = threadIdx.x & 63;
  const float* xr = x + (size_t)row * HDIM;
  float s = 0.f;
#pragma unroll
  for (int i = 0; i < 12; ++i) s += xr[lane + i * 64] * gw[lane + i * 64];
#pragma unroll
  for (int o = 32; o > 0; o >>= 1) s += __shfl_xor(s, o);
  if (lane == 0) out[row] = s + gb[0];
}

// ---------------- host ----------------
extern "C" void kernel_launch(void* const* d_in, const int* in_sizes, int n_in,
                              void* d_out, int out_size, void* d_ws, size_t ws_size,
                              hipStream_t stream)
{
  const float* emb = (const float*)d_in[0];
  const float* pos = (const float*)d_in[2];
  const float* tte = (const float*)d_in[3];
  const float* eg  = (const float*)d_in[4];
  const float* eb  = (const float*)d_in[5];
  const float* Wq  = (const float*)d_in[6];
  const float* bq  = (const float*)d_in[7];
  const float* Wk  = (const float*)d_in[8];
  const float* bk  = (const float*)d_in[9];
  const float* Wv  = (const float*)d_in[10];
  const float* bv  = (const float*)d_in[11];
  const float* Wo  = (const float*)d_in[12];
  const float* bo  = (const float*)d_in[13];
  const float* g1  = (const float*)d_in[14];
  const float* be1 = (const float*)d_in[15];
  const float* Wi  = (const float*)d_in[16];
  const float* bi  = (const float*)d_in[17];
  const float* Wo2 = (const float*)d_in[18];
  const float* bo2 = (const float*)d_in[19];
  const float* g2  = (const float*)d_in[20];
  const float* be2 = (const float*)d_in[21];
  const float* gw  = (const float*)d_in[22];
  const float* gb  = (const float*)d_in[23];

  char* wsp = (char*)d_ws;
  bf16* wt   = (bf16*)wsp;
  bf16* xb   = (bf16*)(wsp + 14155776);
  bf16* qkvb = (bf16*)(wsp + 23592960);
  float* tmp = (float*)(wsp + 61341696);
  bf16* attb = qkvb + (size_t)3 * 4718592;
  bf16* ffb  = qkvb;                 // alias: q/k/v/att dead when FFN1 runs
  float* x   = (float*)d_out;        // f32 residual stream lives in d_out
  float* gate = x + 4718592;

  embed_ln<<<6144, 256, 0, stream>>>(emb, pos, tte, eg, eb, x, xb);

  for (int l = 0; l < 12; ++l) {
    wconv<<<6912, 256, 0, stream>>>(Wq + (size_t)l * 589824, Wk + (size_t)l * 589824,
                                    Wv + (size_t)l * 589824, Wo + (size_t)l * 589824,
                                    Wi + (size_t)l * 2359296, Wo2 + (size_t)l * 2359296, wt);
    // QKV: M=6144 N=2304 K=768 -> 24x9 = 216 blocks
    gemm256<<<216, 512, 0, stream>>>(xb, wt, qkvb,
        bq + l * 768, bk + l * 768, bv + l * 768, 9, 2304, 768, 12, 0);
    attn_mfma<<<dim3(6, 12, 8), 256, 0, stream>>>(qkvb, attb);
    // OProj: N=768 K=768 -> 24x3 = 72 blocks
    gemm256<<<72, 512, 0, stream>>>(attb, wt + 1769472, tmp,
        bo + l * 768, nullptr, nullptr, 3, 768, 768, 12, 3);
    add_ln<<<6144, 256, 0, stream>>>(tmp, x, xb, g1 + l * 768, be1 + l * 768);
    // FFN1: N=3072 K=768 -> 24x12 = 288 blocks
    gemm256<<<288, 512, 0, stream>>>(xb, wt + 2359296, ffb,
        bi + l * 3072, nullptr, nullptr, 12, 3072, 768, 12, 2);
    // FFN2: N=768 K=3072 -> 24x3 = 72 blocks
    gemm256<<<72, 512, 0, stream>>>(ffb, wt + 4718592, tmp,
        bo2 + l * 768, nullptr, nullptr, 3, 768, 3072, 48, 3);
    add_ln<<<6144, 256, 0, stream>>>(tmp, x, xb, g2 + l * 768, be2 + l * 768);
  }

  gate_kernel<<<1536, 256, 0, stream>>>(x, gw, gb, gate);
}